// Round 9
// baseline (119.902 us; speedup 1.0000x reference)
//
#include <hip/hip_runtime.h>

// hinge one-vs-rest loss:
//   loss = (1/B) * sum_{all elements} max(1 - o*sign(l), 0),  B = 16384
// R8 post-mortem: mod-residue ticket test fires EARLY when the poisoned
// counter's initial value isn't ≡0 mod group size -> finisher read unwritten
// slots (absmax 116-488, nondeterministic). R7 only passed because partials
// are call-invariant. Fix: hipMemsetAsync zeroes the counter region every
// call (graph-safe, proven R1), so "t == N-1" is an exact last-arrival test.
// Stage1 geometry byte-identical to R4 (best measured: 2000 x 256 x 8).

constexpr int BLOCK  = 256;
constexpr int UNROLL = 8;               // float4 per thread per array
constexpr int TILE   = BLOCK * UNROLL;  // 2048 float4 per block
constexpr int GSIZE  = 40;              // blocks per group
constexpr int NG     = 50;              // groups (grid = 2000 = 50*40)

__device__ __forceinline__ float block_reduce(float acc, float* wave_sums) {
    #pragma unroll
    for (int off = 32; off > 0; off >>= 1)
        acc += __shfl_down(acc, off, 64);
    const int lane = threadIdx.x & 63;
    const int wid  = threadIdx.x >> 6;
    if (lane == 0) wave_sums[wid] = acc;
    __syncthreads();
    float s = 0.0f;
    #pragma unroll
    for (int w = 0; w < BLOCK / 64; ++w) s += wave_sums[w];
    return s;
}

// Fused: R4 stage1 + hierarchical last-block finish (counters pre-zeroed).
__global__ __launch_bounds__(BLOCK) void hinge_fused_hier(
    const float4* __restrict__ out4,
    const float4* __restrict__ lab4,
    float* __restrict__ partials,      // [2000]
    float* __restrict__ gsum,          // [NG]
    unsigned* __restrict__ tcnt,       // [NG]  zeroed each call
    unsigned* __restrict__ final_t,    // [1]   zeroed each call
    float* __restrict__ loss,
    float inv_b)
{
    const int tid = threadIdx.x;
    const size_t base = (size_t)blockIdx.x * TILE + tid;
    const float4* __restrict__ po = out4 + base;
    const float4* __restrict__ pl = lab4 + base;

    // ---- stage1: identical load/compute structure to R4 ----
    float4 o[UNROLL], l[UNROLL];
    #pragma unroll
    for (int u = 0; u < UNROLL; ++u) o[u] = po[u * BLOCK];
    #pragma unroll
    for (int u = 0; u < UNROLL; ++u) l[u] = pl[u * BLOCK];

    float a0 = 0.f, a1 = 0.f, a2 = 0.f, a3 = 0.f;
    #pragma unroll
    for (int u = 0; u < UNROLL; ++u) {
        a0 += fmaxf(1.0f - (l[u].x >= 0.0f ? o[u].x : -o[u].x), 0.0f);
        a1 += fmaxf(1.0f - (l[u].y >= 0.0f ? o[u].y : -o[u].y), 0.0f);
        a2 += fmaxf(1.0f - (l[u].z >= 0.0f ? o[u].z : -o[u].z), 0.0f);
        a3 += fmaxf(1.0f - (l[u].w >= 0.0f ? o[u].w : -o[u].w), 0.0f);
    }
    float acc = (a0 + a1) + (a2 + a3);

    __shared__ float wave_sums[BLOCK / 64];
    __shared__ unsigned flag1, flag2;
    const float s = block_reduce(acc, wave_sums);

    // ---- level 1: per-group ticket, counters start at 0 every call ----
    const int g = blockIdx.x / GSIZE;
    if (tid == 0) {
        partials[blockIdx.x] = s;
        __threadfence();                               // release partial
        const unsigned t = atomicAdd(&tcnt[g], 1u);
        flag1 = (t == (unsigned)(GSIZE - 1)) ? 1u : 0u; // exact last arrival
    }
    __syncthreads();
    if (!flag1) return;

    // ---- group-last: reduce this group's 40 partials ----
    __threadfence();                                   // acquire partials
    float ga = (tid < GSIZE) ? partials[g * GSIZE + tid] : 0.0f;
    const float gs = block_reduce(ga, wave_sums);

    // ---- level 2: final ticket (50 arrivals) ----
    if (tid == 0) {
        gsum[g] = gs;
        __threadfence();                               // release gsum
        const unsigned t2 = atomicAdd(final_t, 1u);
        flag2 = (t2 == (unsigned)(NG - 1)) ? 1u : 0u;
    }
    __syncthreads();
    if (!flag2) return;

    // ---- final-last: reduce 50 group sums, write loss ----
    __threadfence();                                   // acquire gsums
    float fa = (tid < NG) ? gsum[tid] : 0.0f;
    const float tot = block_reduce(fa, wave_sums);
    if (tid == 0) loss[0] = tot * inv_b;               // full overwrite
}

// ---- Fallback for non-exact sizes: guarded two-stage (R4) ----
__global__ __launch_bounds__(BLOCK) void hinge_stage1_guarded(
    const float4* __restrict__ out4,
    const float4* __restrict__ lab4,
    float* __restrict__ partials,
    int n4)
{
    const int tid = threadIdx.x;
    const long long base = (long long)blockIdx.x * TILE + tid;
    float acc = 0.0f;
    #pragma unroll
    for (int u = 0; u < UNROLL; ++u) {
        const long long idx = base + (long long)u * BLOCK;
        if (idx < n4) {
            const float4 o = out4[idx];
            const float4 l = lab4[idx];
            acc += fmaxf(1.0f - (l.x >= 0.0f ? o.x : -o.x), 0.0f);
            acc += fmaxf(1.0f - (l.y >= 0.0f ? o.y : -o.y), 0.0f);
            acc += fmaxf(1.0f - (l.z >= 0.0f ? o.z : -o.z), 0.0f);
            acc += fmaxf(1.0f - (l.w >= 0.0f ? o.w : -o.w), 0.0f);
        }
    }
    __shared__ float wave_sums[BLOCK / 64];
    const float s = block_reduce(acc, wave_sums);
    if (tid == 0) partials[blockIdx.x] = s;
}

__global__ __launch_bounds__(BLOCK) void hinge_stage2_kernel(
    const float* __restrict__ partials,
    float* __restrict__ loss,
    int n_partials, float inv_b)
{
    float acc = 0.0f;
    for (int i = threadIdx.x; i < n_partials; i += BLOCK)
        acc += partials[i];
    __shared__ float wave_sums[BLOCK / 64];
    const float s = block_reduce(acc, wave_sums);
    if (threadIdx.x == 0) loss[0] = s * inv_b;
}

extern "C" void kernel_launch(void* const* d_in, const int* in_sizes, int n_in,
                              void* d_out, int out_size, void* d_ws, size_t ws_size,
                              hipStream_t stream) {
    const float* outputs = (const float*)d_in[0];
    const float* labels  = (const float*)d_in[1];
    float* loss = (float*)d_out;

    // d_ws layout:
    //   [0]      final ticket (unsigned)        } zeroed every call
    //   [64]     tcnt[NG] (unsigned)            }
    //   [4096]   partials[2000] (float)   (written before read)
    //   [16384]  gsum[NG] (float)         (written before read)
    unsigned* final_t  = (unsigned*)d_ws;
    unsigned* tcnt     = (unsigned*)((char*)d_ws + 64);
    float*    partials = (float*)((char*)d_ws + 4096);
    float*    gsum     = (float*)((char*)d_ws + 16384);

    const long long n = (long long)in_sizes[0];   // 16,384,000
    const int n4 = (int)(n / 4);                  // 4,096,000
    const float inv_b = 1.0f / 16384.0f;
    const int grid = (n4 + TILE - 1) / TILE;      // 2000

    if (n4 % TILE == 0 && grid == GSIZE * NG) {
        // Zero the ticket counters: exact last-arrival test needs t0 == 0.
        hipMemsetAsync(d_ws, 0, 4096, stream);
        hinge_fused_hier<<<grid, BLOCK, 0, stream>>>(
            (const float4*)outputs, (const float4*)labels,
            partials, gsum, tcnt, final_t, loss, inv_b);
    } else {
        hinge_stage1_guarded<<<grid, BLOCK, 0, stream>>>(
            (const float4*)outputs, (const float4*)labels, partials, n4);
        hinge_stage2_kernel<<<1, BLOCK, 0, stream>>>(partials, loss, grid, inv_b);
    }
}

// Round 10
// 26.401 us; speedup vs baseline: 4.5416x; 4.5416x over previous
//
#include <hip/hip_runtime.h>

// hinge one-vs-rest loss:
//   loss = (1/B) * sum_{all elements} max(1 - o*sign(l), 0),  B = 16384
// R9 post-mortem: ALL in-kernel cross-block finishes regressed (R1/R2 atomic
// serialization ~25ns/arrival; R6 grid.sync 254us; R7 39us; R9 fence storm
// 120us -- device-scope __threadfence = L2 writeback/invalidate on 8
// non-coherent XCDs, poisoning the stream for co-resident blocks). The
// kernel boundary is the cheapest device-wide fence: two-stage R4 design
// stands. This round: R4 byte-identical + ONE variable -- nontemporal loads
// in stage1 (stream never re-reads; skip L2 allocation; 16MB/XCD stream vs
// 4MB L2).

constexpr int BLOCK  = 256;
constexpr int UNROLL = 8;               // float4 per thread per array
constexpr int TILE   = BLOCK * UNROLL;  // 2048 float4 per block

typedef float f32x4 __attribute__((ext_vector_type(4)));

__device__ __forceinline__ float block_reduce(float acc, float* wave_sums) {
    #pragma unroll
    for (int off = 32; off > 0; off >>= 1)
        acc += __shfl_down(acc, off, 64);
    const int lane = threadIdx.x & 63;
    const int wid  = threadIdx.x >> 6;
    if (lane == 0) wave_sums[wid] = acc;
    __syncthreads();
    float s = 0.0f;
    #pragma unroll
    for (int w = 0; w < BLOCK / 64; ++w) s += wave_sums[w];
    return s;
}

// Stage 1 (exact tiling): per-block partials -> d_ws. Nontemporal streams.
__global__ __launch_bounds__(BLOCK) void hinge_stage1_exact(
    const f32x4* __restrict__ out4,
    const f32x4* __restrict__ lab4,
    float* __restrict__ partials)
{
    const int tid = threadIdx.x;
    const size_t base = (size_t)blockIdx.x * TILE + tid;
    const f32x4* __restrict__ po = out4 + base;
    const f32x4* __restrict__ pl = lab4 + base;

    f32x4 o[UNROLL], l[UNROLL];
    #pragma unroll
    for (int u = 0; u < UNROLL; ++u) o[u] = __builtin_nontemporal_load(po + u * BLOCK);
    #pragma unroll
    for (int u = 0; u < UNROLL; ++u) l[u] = __builtin_nontemporal_load(pl + u * BLOCK);

    float a0 = 0.f, a1 = 0.f, a2 = 0.f, a3 = 0.f;
    #pragma unroll
    for (int u = 0; u < UNROLL; ++u) {
        a0 += fmaxf(1.0f - (l[u].x >= 0.0f ? o[u].x : -o[u].x), 0.0f);
        a1 += fmaxf(1.0f - (l[u].y >= 0.0f ? o[u].y : -o[u].y), 0.0f);
        a2 += fmaxf(1.0f - (l[u].z >= 0.0f ? o[u].z : -o[u].z), 0.0f);
        a3 += fmaxf(1.0f - (l[u].w >= 0.0f ? o[u].w : -o[u].w), 0.0f);
    }
    float acc = (a0 + a1) + (a2 + a3);

    __shared__ float wave_sums[BLOCK / 64];
    const float s = block_reduce(acc, wave_sums);
    if (tid == 0) partials[blockIdx.x] = s;
}

// Guarded fallback (only if n4 % TILE != 0).
__global__ __launch_bounds__(BLOCK) void hinge_stage1_guarded(
    const float4* __restrict__ out4,
    const float4* __restrict__ lab4,
    float* __restrict__ partials,
    int n4)
{
    const int tid = threadIdx.x;
    const long long base = (long long)blockIdx.x * TILE + tid;
    float acc = 0.0f;
    #pragma unroll
    for (int u = 0; u < UNROLL; ++u) {
        const long long idx = base + (long long)u * BLOCK;
        if (idx < n4) {
            const float4 o = out4[idx];
            const float4 l = lab4[idx];
            acc += fmaxf(1.0f - (l.x >= 0.0f ? o.x : -o.x), 0.0f);
            acc += fmaxf(1.0f - (l.y >= 0.0f ? o.y : -o.y), 0.0f);
            acc += fmaxf(1.0f - (l.z >= 0.0f ? o.z : -o.z), 0.0f);
            acc += fmaxf(1.0f - (l.w >= 0.0f ? o.w : -o.w), 0.0f);
        }
    }
    __shared__ float wave_sums[BLOCK / 64];
    const float s = block_reduce(acc, wave_sums);
    if (tid == 0) partials[blockIdx.x] = s;
}

// Stage 2: one block reduces the partials and writes the scalar loss.
__global__ __launch_bounds__(BLOCK) void hinge_stage2_kernel(
    const float* __restrict__ partials,
    float* __restrict__ loss,
    int n_partials, float inv_b)
{
    float acc = 0.0f;
    for (int i = threadIdx.x; i < n_partials; i += BLOCK)
        acc += partials[i];
    __shared__ float wave_sums[BLOCK / 64];
    const float s = block_reduce(acc, wave_sums);
    if (threadIdx.x == 0) loss[0] = s * inv_b;  // full overwrite
}

extern "C" void kernel_launch(void* const* d_in, const int* in_sizes, int n_in,
                              void* d_out, int out_size, void* d_ws, size_t ws_size,
                              hipStream_t stream) {
    const float* outputs = (const float*)d_in[0];
    const float* labels  = (const float*)d_in[1];
    float* loss     = (float*)d_out;
    float* partials = (float*)d_ws;   // grid floats, written before read

    const long long n = (long long)in_sizes[0];   // 16,384,000
    const int n4 = (int)(n / 4);                  // 4,096,000
    const float inv_b = 1.0f / 16384.0f;

    const int grid = (n4 + TILE - 1) / TILE;      // 2000 blocks

    if (n4 % TILE == 0) {
        hinge_stage1_exact<<<grid, BLOCK, 0, stream>>>(
            (const f32x4*)outputs, (const f32x4*)labels, partials);
    } else {
        hinge_stage1_guarded<<<grid, BLOCK, 0, stream>>>(
            (const float4*)outputs, (const float4*)labels, partials, n4);
    }
    hinge_stage2_kernel<<<1, BLOCK, 0, stream>>>(partials, loss, grid, inv_b);
}

// Round 11
// 24.927 us; speedup vs baseline: 4.8102x; 1.0591x over previous
//
#include <hip/hip_runtime.h>

// hinge one-vs-rest loss:
//   loss = (1/B) * sum_{all elements} max(1 - o*sign(l), 0),  B = 16384
// R10: nt-loads win kept (27.3 -> 26.4us; FETCH unchanged -> skips L2 only).
// Accounting: stage1 ~22.8us = 5.75 TB/s (91% of m13 copy ceiling) + ~3.5us
// structural two-launch tail (all in-kernel finishes regressed 1.4-10x).
// Final probe: is the L3-resident half issue-limited? Single variable:
// 1024-thread blocks x UNROLL 4 (1000 blocks exact, 16 waves/block -> 2x
// resident waves/CU). Same total load instrs, same nt loads.

constexpr int BLOCK  = 1024;
constexpr int UNROLL = 4;               // float4 per thread per array
constexpr int TILE   = BLOCK * UNROLL;  // 4096 float4 per block
constexpr int NWAVES = BLOCK / 64;      // 16

typedef float f32x4 __attribute__((ext_vector_type(4)));

__device__ __forceinline__ float block_reduce(float acc, float* wave_sums) {
    #pragma unroll
    for (int off = 32; off > 0; off >>= 1)
        acc += __shfl_down(acc, off, 64);
    const int lane = threadIdx.x & 63;
    const int wid  = threadIdx.x >> 6;
    if (lane == 0) wave_sums[wid] = acc;
    __syncthreads();
    float s = 0.0f;
    #pragma unroll
    for (int w = 0; w < NWAVES; ++w) s += wave_sums[w];
    return s;
}

// Stage 1 (exact tiling): per-block partials -> d_ws. Nontemporal streams.
__global__ __launch_bounds__(BLOCK) void hinge_stage1_exact(
    const f32x4* __restrict__ out4,
    const f32x4* __restrict__ lab4,
    float* __restrict__ partials)
{
    const int tid = threadIdx.x;
    const size_t base = (size_t)blockIdx.x * TILE + tid;
    const f32x4* __restrict__ po = out4 + base;
    const f32x4* __restrict__ pl = lab4 + base;

    f32x4 o[UNROLL], l[UNROLL];
    #pragma unroll
    for (int u = 0; u < UNROLL; ++u) o[u] = __builtin_nontemporal_load(po + u * BLOCK);
    #pragma unroll
    for (int u = 0; u < UNROLL; ++u) l[u] = __builtin_nontemporal_load(pl + u * BLOCK);

    float a0 = 0.f, a1 = 0.f, a2 = 0.f, a3 = 0.f;
    #pragma unroll
    for (int u = 0; u < UNROLL; ++u) {
        a0 += fmaxf(1.0f - (l[u].x >= 0.0f ? o[u].x : -o[u].x), 0.0f);
        a1 += fmaxf(1.0f - (l[u].y >= 0.0f ? o[u].y : -o[u].y), 0.0f);
        a2 += fmaxf(1.0f - (l[u].z >= 0.0f ? o[u].z : -o[u].z), 0.0f);
        a3 += fmaxf(1.0f - (l[u].w >= 0.0f ? o[u].w : -o[u].w), 0.0f);
    }
    float acc = (a0 + a1) + (a2 + a3);

    __shared__ float wave_sums[NWAVES];
    const float s = block_reduce(acc, wave_sums);
    if (tid == 0) partials[blockIdx.x] = s;
}

// Guarded fallback (only if n4 % TILE != 0): 256-thread version.
__global__ __launch_bounds__(256) void hinge_stage1_guarded(
    const float4* __restrict__ out4,
    const float4* __restrict__ lab4,
    float* __restrict__ partials,
    int n4)
{
    const int tid = threadIdx.x;
    const long long base = (long long)blockIdx.x * (256LL * 8) + tid;
    float acc = 0.0f;
    #pragma unroll
    for (int u = 0; u < 8; ++u) {
        const long long idx = base + (long long)u * 256;
        if (idx < n4) {
            const float4 o = out4[idx];
            const float4 l = lab4[idx];
            acc += fmaxf(1.0f - (l.x >= 0.0f ? o.x : -o.x), 0.0f);
            acc += fmaxf(1.0f - (l.y >= 0.0f ? o.y : -o.y), 0.0f);
            acc += fmaxf(1.0f - (l.z >= 0.0f ? o.z : -o.z), 0.0f);
            acc += fmaxf(1.0f - (l.w >= 0.0f ? o.w : -o.w), 0.0f);
        }
    }
    #pragma unroll
    for (int off = 32; off > 0; off >>= 1)
        acc += __shfl_down(acc, off, 64);
    __shared__ float ws[4];
    if ((tid & 63) == 0) ws[tid >> 6] = acc;
    __syncthreads();
    if (tid == 0) partials[blockIdx.x] = ws[0] + ws[1] + ws[2] + ws[3];
}

// Stage 2: one block reduces the partials and writes the scalar loss.
__global__ __launch_bounds__(256) void hinge_stage2_kernel(
    const float* __restrict__ partials,
    float* __restrict__ loss,
    int n_partials, float inv_b)
{
    float acc = 0.0f;
    for (int i = threadIdx.x; i < n_partials; i += 256)
        acc += partials[i];
    #pragma unroll
    for (int off = 32; off > 0; off >>= 1)
        acc += __shfl_down(acc, off, 64);
    __shared__ float ws[4];
    if ((threadIdx.x & 63) == 0) ws[threadIdx.x >> 6] = acc;
    __syncthreads();
    if (threadIdx.x == 0) loss[0] = (ws[0] + ws[1] + ws[2] + ws[3]) * inv_b;
}

extern "C" void kernel_launch(void* const* d_in, const int* in_sizes, int n_in,
                              void* d_out, int out_size, void* d_ws, size_t ws_size,
                              hipStream_t stream) {
    const float* outputs = (const float*)d_in[0];
    const float* labels  = (const float*)d_in[1];
    float* loss     = (float*)d_out;
    float* partials = (float*)d_ws;   // grid floats, written before read

    const long long n = (long long)in_sizes[0];   // 16,384,000
    const int n4 = (int)(n / 4);                  // 4,096,000
    const float inv_b = 1.0f / 16384.0f;

    if (n4 % TILE == 0) {
        const int grid = n4 / TILE;               // 1000 blocks exact
        hinge_stage1_exact<<<grid, BLOCK, 0, stream>>>(
            (const f32x4*)outputs, (const f32x4*)labels, partials);
        hinge_stage2_kernel<<<1, 256, 0, stream>>>(partials, loss, grid, inv_b);
    } else {
        const int grid = (n4 + 256 * 8 - 1) / (256 * 8);
        hinge_stage1_guarded<<<grid, 256, 0, stream>>>(
            (const float4*)outputs, (const float4*)labels, partials, n4);
        hinge_stage2_kernel<<<1, 256, 0, stream>>>(partials, loss, grid, inv_b);
    }
}